// Round 1
// 86.274 us; speedup vs baseline: 1.0223x; 1.0223x over previous
//
#include <hip/hip_runtime.h>

// Problem: N=2048, M=512, D=128, all fp32.
// Outputs (flat): [0]=min_loss, [1]=wise_min_loss, [2..2+N*D)=z_out.
//
// Timing context (rocprof): the bench window is dominated by two ~40.5us
// 256MiB harness re-poison fills (~81us at 82% HBM peak); our kernels are the
// ~6-7us residual and are VALU-issue-bound. This revision cuts elem-path VALU
// ops bit-exactly:
//   min_n (z-e)^2 == (min_n |z-e|)^2   (monotone square + monotone rounding)
// so the inner op is v_min3_f32 with free |.| input modifiers over 2 n's:
//   1.5 VALU ops/element instead of 3. Square once at store.
//
// Structure: 2 dispatches.
//  k_main (1024 blocks, heterogeneous, LPT-ordered: long sum blocks first):
//    bx in [0,256)   : sum partials. block=(n-block of 256, m-tile of 16);
//                      z row in VGPRs; per-wave min per m; plain store.
//    bx in [256,768) : elem partials. block=(m-group of 8, n-chunk of 256);
//                      thread owns (d, 4 m's); min-abs over chunk in regs
//                      via min3; squared at store.
//    bx in [768,1024): dropout mask; block 768 also zeroes acc/counter.
//  k_fin (64 blocks): min over 8 chunks + sum (elem), min over 32 partials +
//    sum (sum path), atomicAdd into acc, last-block writes out[0..1].
//
// ws layout (floats):
//   [0 .. 524288)        pb_elem[chunk][m][d]   (8*512*128, 2MB)  (squared)
//   [524288 .. 540672)   pb_sum[m][32]          (512*32)
//   [540672 .. +2)       acc[2]
//   [540674]             counter (uint)

#define N_ 2048
#define M_ 512
#define D_ 128
#define PB_SUM  (8 * M_ * D_)          // 524288
#define ACC_OFF (PB_SUM + M_ * 32)     // 540672
#define CNT_OFF (ACC_OFF + 2)

__global__ void __launch_bounds__(256, 2) k_main(
        const float* __restrict__ z, const float* __restrict__ e,
        const float* __restrict__ probs, const float* __restrict__ drop,
        float* __restrict__ out, float* __restrict__ ws) {
    const int bx = blockIdx.x;
    const int t  = threadIdx.x;

    if (bx < 256) {
        // ---- sum partials: per-(n,m) dsum, per-wave min over n ----
        // Longest block type: dispatched first for LPT packing.
        const int b = bx;
        const int nb = b >> 5, mt = b & 31;
        const int n = nb * 256 + t;
        const int m0 = mt * 16;

        float4 zr[32];
        const float4* z4 = reinterpret_cast<const float4*>(z) + n * 32;
        #pragma unroll
        for (int j = 0; j < 32; ++j) zr[j] = z4[j];

        const float4* e4 = reinterpret_cast<const float4*>(e);
        const int w = t >> 6;
        for (int mi = 0; mi < 16; mi += 2) {
            const int ma = m0 + mi;
            const int mb = ma + 1;
            float a0 = 0.f, a1 = 0.f, a2 = 0.f, a3 = 0.f;
            float b0 = 0.f, b1 = 0.f, b2 = 0.f, b3 = 0.f;
            #pragma unroll
            for (int j = 0; j < 32; ++j) {
                float4 ea = e4[ma * 32 + j];    // wave-uniform
                float4 eb = e4[mb * 32 + j];
                float dx, dy, dz, dw;
                dx = zr[j].x - ea.x; a0 = fmaf(dx, dx, a0);
                dy = zr[j].y - ea.y; a1 = fmaf(dy, dy, a1);
                dz = zr[j].z - ea.z; a2 = fmaf(dz, dz, a2);
                dw = zr[j].w - ea.w; a3 = fmaf(dw, dw, a3);
                dx = zr[j].x - eb.x; b0 = fmaf(dx, dx, b0);
                dy = zr[j].y - eb.y; b1 = fmaf(dy, dy, b1);
                dz = zr[j].z - eb.z; b2 = fmaf(dz, dz, b2);
                dw = zr[j].w - eb.w; b3 = fmaf(dw, dw, b3);
            }
            float sa = (a0 + a1) + (a2 + a3);
            float sb = (b0 + b1) + (b2 + b3);
            #pragma unroll
            for (int off = 32; off; off >>= 1) {
                sa = fminf(sa, __shfl_xor(sa, off));
                sb = fminf(sb, __shfl_xor(sb, off));
            }
            if ((t & 63) == 0) {
                ws[PB_SUM + ma * 32 + nb * 4 + w] = sa;
                ws[PB_SUM + mb * 32 + nb * 4 + w] = sb;
            }
        }
    } else if (bx < 768) {
        // ---- elem partials: min-abs over one 256-n chunk for 8 m's ----
        const int eb = bx - 256;
        const int mg = eb >> 3, chunk = eb & 7;
        const int d = t & 127, half = t >> 7;
        const int m0 = mg * 8 + half * 4;
        const int n0 = chunk * 256;

        const float e0 = e[(m0 + 0) * D_ + d];
        const float e1 = e[(m0 + 1) * D_ + d];
        const float e2 = e[(m0 + 2) * D_ + d];
        const float e3 = e[(m0 + 3) * D_ + d];

        float me0 = __uint_as_float(0x7f800000u), me1 = me0, me2 = me0, me3 = me0;
        const float* zp = z + n0 * D_ + d;
        // 2 n's per step: fminf(me, fminf(|a|,|b|)) -> v_min3_f32 with abs mods.
        #pragma unroll 4
        for (int i = 0; i < 256; i += 2) {
            float za = zp[i * D_];
            float zb = zp[i * D_ + D_];
            float a, b;
            a = za - e0; b = zb - e0; me0 = fminf(me0, fminf(fabsf(a), fabsf(b)));
            a = za - e1; b = zb - e1; me1 = fminf(me1, fminf(fabsf(a), fabsf(b)));
            a = za - e2; b = zb - e2; me2 = fminf(me2, fminf(fabsf(a), fabsf(b)));
            a = za - e3; b = zb - e3; me3 = fminf(me3, fminf(fabsf(a), fabsf(b)));
        }
        float* pe = ws + (size_t)chunk * (M_ * D_) + m0 * D_ + d;
        pe[0 * D_] = me0 * me0;   // square of min-abs == min of squares (exact)
        pe[1 * D_] = me1 * me1;
        pe[2 * D_] = me2 * me2;
        pe[3 * D_] = me3 * me3;
    } else {
        // ---- dropout mask; block 768 zeroes acc/counter ----
        const int b = bx - 768;
        const int i = b * 256 + t;              // float4 index, 65536 total
        const int n = i >> 5;
        const float p = probs[n];
        const float4 zv = reinterpret_cast<const float4*>(z)[i];
        const float4 dv = reinterpret_cast<const float4*>(drop)[i];
        float2 lo, hi;
        lo.x = dv.x < p ? zv.x : 0.f;
        lo.y = dv.y < p ? zv.y : 0.f;
        hi.x = dv.z < p ? zv.z : 0.f;
        hi.y = dv.w < p ? zv.w : 0.f;
        float2* o = reinterpret_cast<float2*>(out + 2) + i * 2;
        o[0] = lo;
        o[1] = hi;
        if (b == 0 && t == 0) {
            ws[ACC_OFF] = 0.f;
            ws[ACC_OFF + 1] = 0.f;
            reinterpret_cast<unsigned int*>(ws)[CNT_OFF] = 0u;
        }
    }
}

__device__ __forceinline__ float min4(float4 v) {
    return fminf(fminf(v.x, v.y), fminf(v.z, v.w));
}

__global__ void __launch_bounds__(256) k_fin(float* __restrict__ ws,
                                             float* __restrict__ out) {
    const int b = blockIdx.x, t = threadIdx.x;
    float* acc = ws + ACC_OFF;
    unsigned int* cnt = reinterpret_cast<unsigned int*>(ws) + CNT_OFF;

    // elem: min over 8 chunks of 4 cells, then local sum
    const int cell = b * 1024 + t * 4;
    float4 mv = *reinterpret_cast<const float4*>(ws + cell);
    #pragma unroll
    for (int c = 1; c < 8; ++c) {
        float4 v = *reinterpret_cast<const float4*>(ws + c * (M_ * D_) + cell);
        mv.x = fminf(mv.x, v.x); mv.y = fminf(mv.y, v.y);
        mv.z = fminf(mv.z, v.z); mv.w = fminf(mv.w, v.w);
    }
    float s_elem = (mv.x + mv.y) + (mv.z + mv.w);

    // sum path: m in [b*8, b*8+8), 8 lanes per m cover 32 partials
    float s_sum = 0.f;
    if (t < 64) {
        const int m = b * 8 + (t >> 3);
        const int j = t & 7;
        float4 v = *reinterpret_cast<const float4*>(ws + PB_SUM + m * 32 + j * 4);
        float mn = min4(v);
        mn = fminf(mn, __shfl_xor(mn, 1));
        mn = fminf(mn, __shfl_xor(mn, 2));
        mn = fminf(mn, __shfl_xor(mn, 4));
        if ((t & 7) == 0) s_sum = mn;
    }

    #pragma unroll
    for (int off = 32; off; off >>= 1) {
        s_elem += __shfl_xor(s_elem, off);
        s_sum  += __shfl_xor(s_sum, off);
    }
    __shared__ float sm[8];
    const int w = t >> 6;
    if ((t & 63) == 0) { sm[w] = s_elem; sm[4 + w] = s_sum; }
    __syncthreads();
    if (t == 0) {
        float te = sm[0] + sm[1] + sm[2] + sm[3];
        float ts = sm[4] + sm[5] + sm[6] + sm[7];
        atomicAdd(&acc[0], ts);
        atomicAdd(&acc[1], te);
        __threadfence();
        unsigned int old = atomicAdd(cnt, 1u);
        if (old == 63u) {
            float a0 = atomicAdd(&acc[0], 0.f);   // RMW read: coherent
            float a1 = atomicAdd(&acc[1], 0.f);
            out[0] = a0 * (1.0f / 512.0f);
            out[1] = a1 * (1.0f / 65536.0f);
        }
    }
}

extern "C" void kernel_launch(void* const* d_in, const int* in_sizes, int n_in,
                              void* d_out, int out_size, void* d_ws, size_t ws_size,
                              hipStream_t stream) {
    const float* z     = (const float*)d_in[0];
    const float* e     = (const float*)d_in[1];
    const float* probs = (const float*)d_in[2];
    const float* drop  = (const float*)d_in[3];
    float* out = (float*)d_out;
    float* ws  = (float*)d_ws;

    k_main<<<dim3(1024), dim3(256), 0, stream>>>(z, e, probs, drop, out, ws);
    k_fin<<<dim3(64), dim3(256), 0, stream>>>(ws, out);
}